// Round 20
// baseline (152.062 us; speedup 1.0000x reference)
//
#include <hip/hip_runtime.h>
#include <hip/hip_bf16.h>
#include <cstddef>

#define D_MODEL 1024
#define NHEAD   16
#define HD      64
#define BATCH   2
#define SEQ     2048
#define BH      (BATCH*NHEAD)   // 32

typedef short bf16x8 __attribute__((ext_vector_type(8)));
typedef float f32x4  __attribute__((ext_vector_type(4)));

static __device__ __forceinline__ unsigned short f2bf(float f) {
    __hip_bfloat16 h = __float2bfloat16(f);   // RNE
    return __builtin_bit_cast(unsigned short, h);
}
static __device__ __forceinline__ unsigned int pk2(float a, float b) {
    return (unsigned int)f2bf(a) | ((unsigned int)f2bf(b) << 16);
}

// global -> LDS async DMA, 16B per lane: LDS dest = uniform base + lane*16.
#define GLD16(gp, lp) __builtin_amdgcn_global_load_lds( \
    (const __attribute__((address_space(1))) unsigned int*)(gp), \
    (__attribute__((address_space(3))) unsigned int*)(lp), 16, 0, 0)

// ---------------------------------------------------------------------------
// K0: ONE launch for all input prep. Blocks 0..4095: 32x32 transpose tiles
// (w_qkv -> WqT, w_out -> WoT, fp32->bf16). Blocks 4096..5119: linear
// fp32->bf16 of x. Unchanged (R17-R19).
// ---------------------------------------------------------------------------
__global__ __launch_bounds__(256) void cvt_all_kernel(
    const float* __restrict__ x, const float* __restrict__ Wq,
    const float* __restrict__ Wo, unsigned short* __restrict__ Xb,
    unsigned short* __restrict__ WqT, unsigned short* __restrict__ WoT)
{
    __shared__ float T[32][33];
    const int bid = blockIdx.x;
    const int tid = threadIdx.x;
    if (bid < 4096) {
        const int bx = bid & 127;         // n-tile
        const int k0 = (bid >> 7) * 32;   // k-tile
        const float* W; unsigned short* WT; int N, n0;
        if (bx < 96) { W = Wq; WT = WqT; N = 3072; n0 = bx*32; }
        else         { W = Wo; WT = WoT; N = 1024; n0 = (bx-96)*32; }
        const int r  = tid >> 3;          // 0..31
        const int cg = tid & 7;           // 0..7
        float4 v = *(const float4*)&W[(size_t)(k0 + r)*N + n0 + cg*4];
        T[r][cg*4+0] = v.x; T[r][cg*4+1] = v.y;
        T[r][cg*4+2] = v.z; T[r][cg*4+3] = v.w;
        __syncthreads();
        uint2 w;
        w.x = pk2(T[cg*4+0][r], T[cg*4+1][r]);
        w.y = pk2(T[cg*4+2][r], T[cg*4+3][r]);
        *(uint2*)&WT[(size_t)(n0 + r)*1024 + k0 + cg*4] = w;
    } else {
        const int n8 = (BATCH*SEQ*D_MODEL)/8;
        const int stride = 1024 * 256;
        for (int i = (bid - 4096)*256 + tid; i < n8; i += stride) {
            const float4 a = ((const float4*)x)[i*2];
            const float4 b = ((const float4*)x)[i*2+1];
            uint4 w;
            w.x = pk2(a.x, a.y); w.y = pk2(a.z, a.w);
            w.z = pk2(b.x, b.y); w.w = pk2(b.z, b.w);
            ((uint4*)Xb)[i] = w;
        }
    }
}

// ---------------------------------------------------------------------------
// K1/K3 v2: bf16 MFMA GEMM with global_load_lds staging. Unchanged (R15,
// bit-exact).
// ---------------------------------------------------------------------------
template<int NN, bool QKV>
__global__ __launch_bounds__(256, 2) void gemm_bf16_kernel(
    const unsigned short* __restrict__ A, const unsigned short* __restrict__ BT,
    unsigned short* __restrict__ Qo, unsigned short* __restrict__ Ko,
    unsigned short* __restrict__ Vo, float* __restrict__ Cf)
{
    __shared__ __align__(16) unsigned short As[128*32];
    __shared__ __align__(16) unsigned short Bs[128*32];

    const int tid  = threadIdx.x;
    const int wv   = tid >> 6;
    const int l    = tid & 63;
    const int ln   = l & 15;
    const int lg   = l >> 4;
    const int wrow = (wv >> 1) * 64;
    const int wcol = (wv & 1) * 64;
    const int mtile = blockIdx.y * 128;
    const int ntile = blockIdx.x * 128;

    const int c0 = wv*128 + l;
    const int c1 = c0 + 64;
    const int r0 = c0 >> 2, ks0 = ((c0 & 3) ^ ((r0 + (r0 >> 2)) & 3)) * 8;
    const int r1 = c1 >> 2, ks1 = ((c1 & 3) ^ ((r1 + (r1 >> 2)) & 3)) * 8;
    const size_t gA0 = (size_t)(mtile + r0)*1024 + ks0;
    const size_t gA1 = (size_t)(mtile + r1)*1024 + ks1;
    const size_t gB0 = (size_t)(ntile + r0)*1024 + ks0;
    const size_t gB1 = (size_t)(ntile + r1)*1024 + ks1;
    unsigned short* lA0 = &As[(wv*128     ) * 8];
    unsigned short* lA1 = &As[(wv*128 + 64) * 8];
    unsigned short* lB0 = &Bs[(wv*128     ) * 8];
    unsigned short* lB1 = &Bs[(wv*128 + 64) * 8];

    const int sw = ((lg ^ ((ln + (ln >> 2)) & 3))) * 8;

    f32x4 acc[4][4] = {};

    for (int kb = 0; kb < 32; ++kb) {
        const int koff = kb * 32;
        GLD16(A  + gA0 + koff, lA0);
        GLD16(A  + gA1 + koff, lA1);
        GLD16(BT + gB0 + koff, lB0);
        GLD16(BT + gB1 + koff, lB1);
        __syncthreads();
        bf16x8 af[4], bf[4];
        #pragma unroll
        for (int i = 0; i < 4; ++i)
            af[i] = *(const bf16x8*)&As[(wrow + i*16 + ln)*32 + sw];
        #pragma unroll
        for (int j = 0; j < 4; ++j)
            bf[j] = *(const bf16x8*)&Bs[(wcol + j*16 + ln)*32 + sw];
        #pragma unroll
        for (int i = 0; i < 4; ++i)
            #pragma unroll
            for (int j = 0; j < 4; ++j)
                acc[i][j] = __builtin_amdgcn_mfma_f32_16x16x32_bf16(af[i], bf[j], acc[i][j], 0, 0, 0);
        __syncthreads();
    }

    #pragma unroll
    for (int i = 0; i < 4; ++i) {
        #pragma unroll
        for (int r = 0; r < 4; ++r) {
            const int mm = mtile + wrow + i*16 + lg*4 + r;
            if constexpr (QKV) {
                const int bb = mm >> 11;
                const int ss = mm & 2047;
                #pragma unroll
                for (int j = 0; j < 4; ++j) {
                    const int cb  = ntile + wcol + j*16 + ln;
                    const int wch = cb >> 10;
                    const int rem = cb & 1023;
                    const int h   = rem >> 6;
                    const int dd  = rem & 63;
                    unsigned short* dstBase = (wch == 0) ? Qo : (wch == 1) ? Ko : Vo;
                    dstBase[((size_t)(bb*NHEAD + h)*SEQ + ss)*HD + dd] = f2bf(acc[i][j][r]);
                }
            } else {
                #pragma unroll
                for (int j = 0; j < 4; ++j) {
                    const int cb = ntile + wcol + j*16 + ln;
                    Cf[(size_t)mm*NN + cb] = acc[i][j][r];
                }
            }
        }
    }
}

// ---------------------------------------------------------------------------
// K2 v14: v10 math, restructured for 4 blocks/CU.
//  (a) Pl dropped: P^T goes into the DEAD rows of Vt[buf^1]. At iter t,
//      Vt[buf^1] holds tile t-1's V (consumed before the top barrier ->
//      dead until write_tile(buf^1) later this iter). Wave w's write_tile
//      touches ONLY rows 16w..16w+15 (s_dg=tid>>4) = the same rows wave w
//      uses for its P (rows wv*16+ln), and its P-read precedes its
//      write_tile -> no cross-wave overlap, no extra barrier.
//      LDS 46.6KB -> 36.9KB -> 4 blocks/CU (147.5 < 160KB).
//  (b) Un-paired: grid (32,32) = 1024 blocks, one q-tile each (qt=31-bx,
//      longest first). Critical path ~32 tiles (vs 33), bulk TLP doubles.
//  __launch_bounds__(256,4): VGPR cap 128 >> our ~70.
// ---------------------------------------------------------------------------
__global__ __launch_bounds__(256, 4) void attn_kernel(
    const unsigned short* __restrict__ Qb, const unsigned short* __restrict__ Kb,
    const unsigned short* __restrict__ Vb, unsigned short* __restrict__ AO)
{
    __shared__ __align__(16) unsigned short Ks[2][64][72];  // keys x dims(+pad)
    __shared__ __align__(16) unsigned short Vt[2][64][72];  // dims x keys(+pad); buf^1 rows double as P^T

    const int tid = threadIdx.x;
    const int wv  = tid >> 6;
    const int l   = tid & 63;
    const int ln  = l & 15;
    const int lg  = l >> 4;
    const int bh  = blockIdx.y;
    const int qt  = 31 - blockIdx.x;     // long blocks first
    const int nT  = qt + 1;              // 64-key tiles

    const unsigned short* Qbh = Qb + (size_t)bh*SEQ*HD;
    const unsigned short* Kbh = Kb + (size_t)bh*SEQ*HD;
    const unsigned short* Vbh = Vb + (size_t)bh*SEQ*HD;

    const int s_kl = tid >> 3;
    const int s_d0 = (tid & 7) << 3;
    const int s_dg = tid >> 4;
    const int s_kp = (tid & 15) << 1;

    // T14 split: global->regs (issue early) vs regs->LDS (write late)
    uint4 rk0, rk1;
    uint2 rva0, rvb0, rva1, rvb1;
    auto load_tile = [&](int kt) {
        rk0  = *(const uint4*)&Kbh[(size_t)(kt + s_kl     )*HD + s_d0];
        rk1  = *(const uint4*)&Kbh[(size_t)(kt + s_kl + 32)*HD + s_d0];
        rva0 = *(const uint2*)&Vbh[(size_t)(kt + s_kp     )*HD + s_dg*4];
        rvb0 = *(const uint2*)&Vbh[(size_t)(kt + s_kp + 1 )*HD + s_dg*4];
        rva1 = *(const uint2*)&Vbh[(size_t)(kt + s_kp + 32)*HD + s_dg*4];
        rvb1 = *(const uint2*)&Vbh[(size_t)(kt + s_kp + 33)*HD + s_dg*4];
    };
    auto write_tile = [&](int nb) {
        *(uint4*)&Ks[nb][s_kl     ][s_d0] = rk0;
        *(uint4*)&Ks[nb][s_kl + 32][s_d0] = rk1;
        *(unsigned int*)&Vt[nb][s_dg*4+0][s_kp]    = (rva0.x & 0xffffu) | (rvb0.x << 16);
        *(unsigned int*)&Vt[nb][s_dg*4+1][s_kp]    = (rva0.x >> 16)     | (rvb0.x & 0xffff0000u);
        *(unsigned int*)&Vt[nb][s_dg*4+2][s_kp]    = (rva0.y & 0xffffu) | (rvb0.y << 16);
        *(unsigned int*)&Vt[nb][s_dg*4+3][s_kp]    = (rva0.y >> 16)     | (rvb0.y & 0xffff0000u);
        *(unsigned int*)&Vt[nb][s_dg*4+0][s_kp+32] = (rva1.x & 0xffffu) | (rvb1.x << 16);
        *(unsigned int*)&Vt[nb][s_dg*4+1][s_kp+32] = (rva1.x >> 16)     | (rvb1.x & 0xffff0000u);
        *(unsigned int*)&Vt[nb][s_dg*4+2][s_kp+32] = (rva1.y & 0xffffu) | (rvb1.y << 16);
        *(unsigned int*)&Vt[nb][s_dg*4+3][s_kp+32] = (rva1.y >> 16)     | (rvb1.y & 0xffff0000u);
    };

    const int qrow0 = qt*64 + wv*16;
    const bf16x8 q0 = *(const bf16x8*)&Qbh[(size_t)(qrow0 + ln)*HD + lg*8];
    const bf16x8 q1 = *(const bf16x8*)&Qbh[(size_t)(qrow0 + ln)*HD + 32 + lg*8];

    f32x4 o[4] = {};
    float m = -1e30f, lsum = 0.f;

    // prologue: tile 0 staged synchronously; tile 1 loads issued early
    load_tile(0);
    write_tile(0);
    if (nT > 1) load_tile(64);

    for (int t = 0; t < nT; ++t) {
        __syncthreads();                     // publishes buf[t&1]
        const int buf = t & 1;
        const int kt = t * 64;

        // ---- QK^T swapped: S^T(64keys x 16q)
        f32x4 s[4];
        #pragma unroll
        for (int g = 0; g < 4; ++g) {
            bf16x8 ka = *(const bf16x8*)&Ks[buf][g*16 + ln][lg*8];
            bf16x8 kb = *(const bf16x8*)&Ks[buf][g*16 + ln][32 + lg*8];
            f32x4 sg = {};
            sg = __builtin_amdgcn_mfma_f32_16x16x32_bf16(ka, q0, sg, 0, 0, 0);
            sg = __builtin_amdgcn_mfma_f32_16x16x32_bf16(kb, q1, sg, 0, 0, 0);
            s[g] = sg;
        }

        const int qg = qrow0 + ln;
        const int kbase = kt + lg*4;
        float mx = -1e30f;
        #pragma unroll
        for (int g = 0; g < 4; ++g) {
            #pragma unroll
            for (int r = 0; r < 4; ++r) {
                float v = s[g][r] * 0.125f;
                v = (kbase + g*16 + r > qg) ? -1e30f : v;
                s[g][r] = v;
                mx = fmaxf(mx, v);
            }
        }
        mx = fmaxf(mx, __shfl_xor(mx, 16));
        mx = fmaxf(mx, __shfl_xor(mx, 32));

        if (__any(mx > m)) {
            const float mnew = fmaxf(m, mx);
            const float alpha = __expf(m - mnew);
            m = mnew;
            lsum *= alpha;
            #pragma unroll
            for (int f = 0; f < 4; ++f)
                #pragma unroll
                for (int r = 0; r < 4; ++r) o[f][r] *= alpha;
        }
        float ps = 0.f;
        #pragma unroll
        for (int g = 0; g < 4; ++g) {
            #pragma unroll
            for (int r = 0; r < 4; ++r) {
                const float e = __expf(s[g][r] - m);
                s[g][r] = e;
                ps += e;
            }
        }
        ps += __shfl_xor(ps, 16);
        ps += __shfl_xor(ps, 32);
        lsum += ps;

        // ---- P^T -> dead rows of Vt[buf^1] (own wave's rows only)
        unsigned short* prow = &Vt[buf ^ 1][wv*16 + ln][0];
        #pragma unroll
        for (int g = 0; g < 4; ++g) {
            unsigned long long w =
                (unsigned long long)pk2(s[g][0], s[g][1]) |
                ((unsigned long long)pk2(s[g][2], s[g][3]) << 32);
            *(unsigned long long*)&prow[g*16 + lg*4] = w;
        }
        bf16x8 pb0 = *(const bf16x8*)&prow[lg*8];
        bf16x8 pb1 = *(const bf16x8*)&prow[32 + lg*8];

        // ---- PV swapped: O^T += V^T * P^T
        #pragma unroll
        for (int f = 0; f < 4; ++f) {
            bf16x8 v0 = *(const bf16x8*)&Vt[buf][f*16 + ln][lg*8];
            bf16x8 v1 = *(const bf16x8*)&Vt[buf][f*16 + ln][32 + lg*8];
            o[f] = __builtin_amdgcn_mfma_f32_16x16x32_bf16(v0, pb0, o[f], 0, 0, 0);
            o[f] = __builtin_amdgcn_mfma_f32_16x16x32_bf16(v1, pb1, o[f], 0, 0, 0);
        }

        // ---- late stage write for t+1 (own rows; after own P-read),
        // then issue loads for t+2
        if (t + 1 < nT) {
            write_tile(buf ^ 1);
            if (t + 2 < nT) load_tile((t + 2) * 64);
        }
    }

    // ---- epilogue
    {
        const int bb = bh >> 4;
        const int h  = bh & 15;
        const float inv = 1.f / lsum;
        const size_t base = ((size_t)bb*SEQ + qrow0 + ln)*D_MODEL + h*HD + lg*4;
        #pragma unroll
        for (int f = 0; f < 4; ++f) {
            uint2 w;
            w.x = pk2(o[f][0]*inv, o[f][1]*inv);
            w.y = pk2(o[f][2]*inv, o[f][3]*inv);
            *(uint2*)&AO[base + f*16] = w;
        }
    }
}

// ---------------------------------------------------------------------------
extern "C" void kernel_launch(void* const* d_in, const int* in_sizes, int n_in,
                              void* d_out, int out_size, void* d_ws, size_t ws_size,
                              hipStream_t stream)
{
    const float* x     = (const float*)d_in[0];   // (2,2048,1024)
    const float* w_qkv = (const float*)d_in[1];   // (1024,3072)
    const float* w_out = (const float*)d_in[2];   // (1024,1024)
    float* out = (float*)d_out;                   // (2,2048,1024)

    const size_t nX  = (size_t)BATCH*SEQ*D_MODEL;      // 4 Mi
    const size_t nWq = (size_t)D_MODEL*3*D_MODEL;      // 3 Mi
    const size_t nWo = (size_t)D_MODEL*D_MODEL;        // 1 Mi
    const size_t per = (size_t)BH * SEQ * HD;          // 4 Mi

    unsigned short* Xb   = (unsigned short*)d_ws;      // bf16 x (M x K)
    unsigned short* WqT  = Xb   + nX;                  // bf16 w_qkv^T
    unsigned short* WoT  = WqT  + nWq;                 // bf16 w_out^T
    unsigned short* Qb   = WoT  + nWo;
    unsigned short* Kb   = Qb + per;
    unsigned short* Vb   = Kb + per;
    unsigned short* AOb  = Vb + per;                   // bf16 (B,S,D)

    // all input prep in one launch: 4096 transpose blocks + 1024 cvt blocks
    cvt_all_kernel<<<5120, 256, 0, stream>>>(x, w_qkv, w_out, Xb, WqT, WoT);

    gemm_bf16_kernel<3*D_MODEL, true><<<dim3(24, 32), 256, 0, stream>>>(
        Xb, WqT, Qb, Kb, Vb, nullptr);
    // causal attention: un-paired, grid = (32, 32) = 1024 blocks, 4/CU
    attn_kernel<<<dim3(32, BH), 256, 0, stream>>>(Qb, Kb, Vb, AOb);
    gemm_bf16_kernel<D_MODEL, false><<<dim3(8, 32), 256, 0, stream>>>(
        AOb, WoT, nullptr, nullptr, nullptr, out);
}

// Round 21
// 123.079 us; speedup vs baseline: 1.2355x; 1.2355x over previous
//
#include <hip/hip_runtime.h>
#include <hip/hip_bf16.h>
#include <cstddef>

#define D_MODEL 1024
#define NHEAD   16
#define HD      64
#define BATCH   2
#define SEQ     2048
#define BH      (BATCH*NHEAD)   // 32

typedef short bf16x8 __attribute__((ext_vector_type(8)));
typedef float f32x4  __attribute__((ext_vector_type(4)));

static __device__ __forceinline__ unsigned short f2bf(float f) {
    __hip_bfloat16 h = __float2bfloat16(f);   // RNE
    return __builtin_bit_cast(unsigned short, h);
}
static __device__ __forceinline__ unsigned int pk2(float a, float b) {
    return (unsigned int)f2bf(a) | ((unsigned int)f2bf(b) << 16);
}

// global -> LDS async DMA, 16B per lane: LDS dest = uniform base + lane*16.
#define GLD16(gp, lp) __builtin_amdgcn_global_load_lds( \
    (const __attribute__((address_space(1))) unsigned int*)(gp), \
    (__attribute__((address_space(3))) unsigned int*)(lp), 16, 0, 0)

// ---------------------------------------------------------------------------
// K0: ONE launch for all input prep. Blocks 0..4095: 32x32 transpose tiles
// (w_qkv -> WqT, w_out -> WoT, fp32->bf16). Blocks 4096..5119: linear
// fp32->bf16 of x. Unchanged (R17-R19).
// ---------------------------------------------------------------------------
__global__ __launch_bounds__(256) void cvt_all_kernel(
    const float* __restrict__ x, const float* __restrict__ Wq,
    const float* __restrict__ Wo, unsigned short* __restrict__ Xb,
    unsigned short* __restrict__ WqT, unsigned short* __restrict__ WoT)
{
    __shared__ float T[32][33];
    const int bid = blockIdx.x;
    const int tid = threadIdx.x;
    if (bid < 4096) {
        const int bx = bid & 127;         // n-tile
        const int k0 = (bid >> 7) * 32;   // k-tile
        const float* W; unsigned short* WT; int N, n0;
        if (bx < 96) { W = Wq; WT = WqT; N = 3072; n0 = bx*32; }
        else         { W = Wo; WT = WoT; N = 1024; n0 = (bx-96)*32; }
        const int r  = tid >> 3;          // 0..31
        const int cg = tid & 7;           // 0..7
        float4 v = *(const float4*)&W[(size_t)(k0 + r)*N + n0 + cg*4];
        T[r][cg*4+0] = v.x; T[r][cg*4+1] = v.y;
        T[r][cg*4+2] = v.z; T[r][cg*4+3] = v.w;
        __syncthreads();
        uint2 w;
        w.x = pk2(T[cg*4+0][r], T[cg*4+1][r]);
        w.y = pk2(T[cg*4+2][r], T[cg*4+3][r]);
        *(uint2*)&WT[(size_t)(n0 + r)*1024 + k0 + cg*4] = w;
    } else {
        const int n8 = (BATCH*SEQ*D_MODEL)/8;
        const int stride = 1024 * 256;
        for (int i = (bid - 4096)*256 + tid; i < n8; i += stride) {
            const float4 a = ((const float4*)x)[i*2];
            const float4 b = ((const float4*)x)[i*2+1];
            uint4 w;
            w.x = pk2(a.x, a.y); w.y = pk2(a.z, a.w);
            w.z = pk2(b.x, b.y); w.w = pk2(b.z, b.w);
            ((uint4*)Xb)[i] = w;
        }
    }
}

// ---------------------------------------------------------------------------
// K1/K3 v3: bf16 MFMA GEMM with global_load_lds staging. R20 change:
// __launch_bounds__(256,3) — gemm_qkv's 768-block grid at 2/CU left a
// 256-block drain tail on a half-idle GPU; 3/CU makes all 768 co-resident
// (one round). VGPR cap 2048/12 waves ≈ 170 > ~100 used -> no spill.
// ---------------------------------------------------------------------------
template<int NN, bool QKV>
__global__ __launch_bounds__(256, 3) void gemm_bf16_kernel(
    const unsigned short* __restrict__ A, const unsigned short* __restrict__ BT,
    unsigned short* __restrict__ Qo, unsigned short* __restrict__ Ko,
    unsigned short* __restrict__ Vo, float* __restrict__ Cf)
{
    __shared__ __align__(16) unsigned short As[128*32];
    __shared__ __align__(16) unsigned short Bs[128*32];

    const int tid  = threadIdx.x;
    const int wv   = tid >> 6;
    const int l    = tid & 63;
    const int ln   = l & 15;
    const int lg   = l >> 4;
    const int wrow = (wv >> 1) * 64;
    const int wcol = (wv & 1) * 64;
    const int mtile = blockIdx.y * 128;
    const int ntile = blockIdx.x * 128;

    const int c0 = wv*128 + l;
    const int c1 = c0 + 64;
    const int r0 = c0 >> 2, ks0 = ((c0 & 3) ^ ((r0 + (r0 >> 2)) & 3)) * 8;
    const int r1 = c1 >> 2, ks1 = ((c1 & 3) ^ ((r1 + (r1 >> 2)) & 3)) * 8;
    const size_t gA0 = (size_t)(mtile + r0)*1024 + ks0;
    const size_t gA1 = (size_t)(mtile + r1)*1024 + ks1;
    const size_t gB0 = (size_t)(ntile + r0)*1024 + ks0;
    const size_t gB1 = (size_t)(ntile + r1)*1024 + ks1;
    unsigned short* lA0 = &As[(wv*128     ) * 8];
    unsigned short* lA1 = &As[(wv*128 + 64) * 8];
    unsigned short* lB0 = &Bs[(wv*128     ) * 8];
    unsigned short* lB1 = &Bs[(wv*128 + 64) * 8];

    const int sw = ((lg ^ ((ln + (ln >> 2)) & 3))) * 8;

    f32x4 acc[4][4] = {};

    for (int kb = 0; kb < 32; ++kb) {
        const int koff = kb * 32;
        GLD16(A  + gA0 + koff, lA0);
        GLD16(A  + gA1 + koff, lA1);
        GLD16(BT + gB0 + koff, lB0);
        GLD16(BT + gB1 + koff, lB1);
        __syncthreads();
        bf16x8 af[4], bf[4];
        #pragma unroll
        for (int i = 0; i < 4; ++i)
            af[i] = *(const bf16x8*)&As[(wrow + i*16 + ln)*32 + sw];
        #pragma unroll
        for (int j = 0; j < 4; ++j)
            bf[j] = *(const bf16x8*)&Bs[(wcol + j*16 + ln)*32 + sw];
        #pragma unroll
        for (int i = 0; i < 4; ++i)
            #pragma unroll
            for (int j = 0; j < 4; ++j)
                acc[i][j] = __builtin_amdgcn_mfma_f32_16x16x32_bf16(af[i], bf[j], acc[i][j], 0, 0, 0);
        __syncthreads();
    }

    #pragma unroll
    for (int i = 0; i < 4; ++i) {
        #pragma unroll
        for (int r = 0; r < 4; ++r) {
            const int mm = mtile + wrow + i*16 + lg*4 + r;
            if constexpr (QKV) {
                const int bb = mm >> 11;
                const int ss = mm & 2047;
                #pragma unroll
                for (int j = 0; j < 4; ++j) {
                    const int cb  = ntile + wcol + j*16 + ln;
                    const int wch = cb >> 10;
                    const int rem = cb & 1023;
                    const int h   = rem >> 6;
                    const int dd  = rem & 63;
                    unsigned short* dstBase = (wch == 0) ? Qo : (wch == 1) ? Ko : Vo;
                    dstBase[((size_t)(bb*NHEAD + h)*SEQ + ss)*HD + dd] = f2bf(acc[i][j][r]);
                }
            } else {
                #pragma unroll
                for (int j = 0; j < 4; ++j) {
                    const int cb = ntile + wcol + j*16 + ln;
                    Cf[(size_t)mm*NN + cb] = acc[i][j][r];
                }
            }
        }
    }
}

// ---------------------------------------------------------------------------
// K2 v13 (R19, 61.4 us — byte-exact revert of R20's v14, which regressed to
// 89.5: unpairing broke load balance — the 32-tile critical-path block
// time-shared with 3 others got SLOWER per tile; occupancy never rose).
// Structure: swapped QK^T (per-lane scalar m/lsum, 2-level shuffles),
// KVBLK=64, paired q-tiles (33 tiles/block, perfectly balanced, 2/CU),
// T14 async-STAGE split, defer-max, dedicated Pl stride-76.
// ---------------------------------------------------------------------------
__global__ __launch_bounds__(256, 2) void attn_kernel(
    const unsigned short* __restrict__ Qb, const unsigned short* __restrict__ Kb,
    const unsigned short* __restrict__ Vb, unsigned short* __restrict__ AO)
{
    __shared__ __align__(16) unsigned short Ks[2][64][72];  // keys x dims(+pad)
    __shared__ __align__(16) unsigned short Vt[2][64][72];  // dims x keys(+pad)
    __shared__ __align__(16) unsigned short Pl[4][16][76];  // per-wave P^T

    const int tid = threadIdx.x;
    const int wv  = tid >> 6;
    const int l   = tid & 63;
    const int ln  = l & 15;
    const int lg  = l >> 4;
    const int bh  = blockIdx.y;
    const int bx  = blockIdx.x;          // 0..15
    const int qtA = 31 - bx;
    const int qtB = bx;
    const int nTA = qtA + 1;
    const int nT  = nTA + qtB + 1;       // 33 always

    const unsigned short* Qbh = Qb + (size_t)bh*SEQ*HD;
    const unsigned short* Kbh = Kb + (size_t)bh*SEQ*HD;
    const unsigned short* Vbh = Vb + (size_t)bh*SEQ*HD;

    const int s_kl = tid >> 3;
    const int s_d0 = (tid & 7) << 3;
    const int s_dg = tid >> 4;
    const int s_kp = (tid & 15) << 1;

    auto ktOf = [&](int t) { return (t < nTA ? t : t - nTA) * 64; };

    // T14 split: global->regs (issue early) vs regs->LDS (write late)
    uint4 rk0, rk1;
    uint2 rva0, rvb0, rva1, rvb1;
    auto load_tile = [&](int kt) {
        rk0  = *(const uint4*)&Kbh[(size_t)(kt + s_kl     )*HD + s_d0];
        rk1  = *(const uint4*)&Kbh[(size_t)(kt + s_kl + 32)*HD + s_d0];
        rva0 = *(const uint2*)&Vbh[(size_t)(kt + s_kp     )*HD + s_dg*4];
        rvb0 = *(const uint2*)&Vbh[(size_t)(kt + s_kp + 1 )*HD + s_dg*4];
        rva1 = *(const uint2*)&Vbh[(size_t)(kt + s_kp + 32)*HD + s_dg*4];
        rvb1 = *(const uint2*)&Vbh[(size_t)(kt + s_kp + 33)*HD + s_dg*4];
    };
    auto write_tile = [&](int nb) {
        *(uint4*)&Ks[nb][s_kl     ][s_d0] = rk0;
        *(uint4*)&Ks[nb][s_kl + 32][s_d0] = rk1;
        *(unsigned int*)&Vt[nb][s_dg*4+0][s_kp]    = (rva0.x & 0xffffu) | (rvb0.x << 16);
        *(unsigned int*)&Vt[nb][s_dg*4+1][s_kp]    = (rva0.x >> 16)     | (rvb0.x & 0xffff0000u);
        *(unsigned int*)&Vt[nb][s_dg*4+2][s_kp]    = (rva0.y & 0xffffu) | (rvb0.y << 16);
        *(unsigned int*)&Vt[nb][s_dg*4+3][s_kp]    = (rva0.y >> 16)     | (rvb0.y & 0xffff0000u);
        *(unsigned int*)&Vt[nb][s_dg*4+0][s_kp+32] = (rva1.x & 0xffffu) | (rvb1.x << 16);
        *(unsigned int*)&Vt[nb][s_dg*4+1][s_kp+32] = (rva1.x >> 16)     | (rvb1.x & 0xffff0000u);
        *(unsigned int*)&Vt[nb][s_dg*4+2][s_kp+32] = (rva1.y & 0xffffu) | (rvb1.y << 16);
        *(unsigned int*)&Vt[nb][s_dg*4+3][s_kp+32] = (rva1.y >> 16)     | (rvb1.y & 0xffff0000u);
    };

    int qrow0 = qtA*64 + wv*16;
    bf16x8 q0 = *(const bf16x8*)&Qbh[(size_t)(qrow0 + ln)*HD + lg*8];
    bf16x8 q1 = *(const bf16x8*)&Qbh[(size_t)(qrow0 + ln)*HD + 32 + lg*8];

    f32x4 o[4] = {};
    float m = -1e30f, lsum = 0.f;

    auto epilogue = [&](int qr0) {
        const int bb = bh >> 4;
        const int h  = bh & 15;
        const float inv = 1.f / lsum;
        const size_t base = ((size_t)bb*SEQ + qr0 + ln)*D_MODEL + h*HD + lg*4;
        #pragma unroll
        for (int f = 0; f < 4; ++f) {
            uint2 w;
            w.x = pk2(o[f][0]*inv, o[f][1]*inv);
            w.y = pk2(o[f][2]*inv, o[f][3]*inv);
            *(uint2*)&AO[base + f*16] = w;
        }
    };

    // prologue: tile 0 staged synchronously; tile 1 loads issued early
    load_tile(0);
    write_tile(0);
    if (nT > 1) load_tile(ktOf(1));

    for (int t = 0; t < nT; ++t) {
        __syncthreads();                     // publishes buf[t&1]
        const int buf = t & 1;
        const int kt = ktOf(t);

        // ---- QK^T swapped: S^T(64keys x 16q)
        f32x4 s[4];
        #pragma unroll
        for (int g = 0; g < 4; ++g) {
            bf16x8 ka = *(const bf16x8*)&Ks[buf][g*16 + ln][lg*8];
            bf16x8 kb = *(const bf16x8*)&Ks[buf][g*16 + ln][32 + lg*8];
            f32x4 sg = {};
            sg = __builtin_amdgcn_mfma_f32_16x16x32_bf16(ka, q0, sg, 0, 0, 0);
            sg = __builtin_amdgcn_mfma_f32_16x16x32_bf16(kb, q1, sg, 0, 0, 0);
            s[g] = sg;
        }

        const int qg = qrow0 + ln;
        const int kbase = kt + lg*4;
        float mx = -1e30f;
        #pragma unroll
        for (int g = 0; g < 4; ++g) {
            #pragma unroll
            for (int r = 0; r < 4; ++r) {
                float v = s[g][r] * 0.125f;
                v = (kbase + g*16 + r > qg) ? -1e30f : v;
                s[g][r] = v;
                mx = fmaxf(mx, v);
            }
        }
        mx = fmaxf(mx, __shfl_xor(mx, 16));
        mx = fmaxf(mx, __shfl_xor(mx, 32));

        if (__any(mx > m)) {
            const float mnew = fmaxf(m, mx);
            const float alpha = __expf(m - mnew);
            m = mnew;
            lsum *= alpha;
            #pragma unroll
            for (int f = 0; f < 4; ++f)
                #pragma unroll
                for (int r = 0; r < 4; ++r) o[f][r] *= alpha;
        }
        float ps = 0.f;
        #pragma unroll
        for (int g = 0; g < 4; ++g) {
            #pragma unroll
            for (int r = 0; r < 4; ++r) {
                const float e = __expf(s[g][r] - m);
                s[g][r] = e;
                ps += e;
            }
        }
        ps += __shfl_xor(ps, 16);
        ps += __shfl_xor(ps, 32);
        lsum += ps;

        #pragma unroll
        for (int g = 0; g < 4; ++g) {
            unsigned long long w =
                (unsigned long long)pk2(s[g][0], s[g][1]) |
                ((unsigned long long)pk2(s[g][2], s[g][3]) << 32);
            *(unsigned long long*)&Pl[wv][ln][g*16 + lg*4] = w;
        }
        bf16x8 pb0 = *(const bf16x8*)&Pl[wv][ln][lg*8];
        bf16x8 pb1 = *(const bf16x8*)&Pl[wv][ln][32 + lg*8];

        #pragma unroll
        for (int f = 0; f < 4; ++f) {
            bf16x8 v0 = *(const bf16x8*)&Vt[buf][f*16 + ln][lg*8];
            bf16x8 v1 = *(const bf16x8*)&Vt[buf][f*16 + ln][32 + lg*8];
            o[f] = __builtin_amdgcn_mfma_f32_16x16x32_bf16(v0, pb0, o[f], 0, 0, 0);
            o[f] = __builtin_amdgcn_mfma_f32_16x16x32_bf16(v1, pb1, o[f], 0, 0, 0);
        }

        // ---- late stage write for t+1, then issue loads for t+2
        if (t + 1 < nT) {
            write_tile(buf ^ 1);
            if (t + 2 < nT) load_tile(ktOf(t + 2));
        }

        // ---- phase boundary: flush q-tile A, reset for q-tile B
        if (t == nTA - 1) {
            epilogue(qrow0);
            qrow0 = qtB*64 + wv*16;
            q0 = *(const bf16x8*)&Qbh[(size_t)(qrow0 + ln)*HD + lg*8];
            q1 = *(const bf16x8*)&Qbh[(size_t)(qrow0 + ln)*HD + 32 + lg*8];
            m = -1e30f; lsum = 0.f;
            #pragma unroll
            for (int f = 0; f < 4; ++f)
                #pragma unroll
                for (int r = 0; r < 4; ++r) o[f][r] = 0.f;
        }
    }
    epilogue(qrow0);   // q-tile B
}

// ---------------------------------------------------------------------------
extern "C" void kernel_launch(void* const* d_in, const int* in_sizes, int n_in,
                              void* d_out, int out_size, void* d_ws, size_t ws_size,
                              hipStream_t stream)
{
    const float* x     = (const float*)d_in[0];   // (2,2048,1024)
    const float* w_qkv = (const float*)d_in[1];   // (1024,3072)
    const float* w_out = (const float*)d_in[2];   // (1024,1024)
    float* out = (float*)d_out;                   // (2,2048,1024)

    const size_t nX  = (size_t)BATCH*SEQ*D_MODEL;      // 4 Mi
    const size_t nWq = (size_t)D_MODEL*3*D_MODEL;      // 3 Mi
    const size_t nWo = (size_t)D_MODEL*D_MODEL;        // 1 Mi
    const size_t per = (size_t)BH * SEQ * HD;          // 4 Mi

    unsigned short* Xb   = (unsigned short*)d_ws;      // bf16 x (M x K)
    unsigned short* WqT  = Xb   + nX;                  // bf16 w_qkv^T
    unsigned short* WoT  = WqT  + nWq;                 // bf16 w_out^T
    unsigned short* Qb   = WoT  + nWo;
    unsigned short* Kb   = Qb + per;
    unsigned short* Vb   = Kb + per;
    unsigned short* AOb  = Vb + per;                   // bf16 (B,S,D)

    // all input prep in one launch: 4096 transpose blocks + 1024 cvt blocks
    cvt_all_kernel<<<5120, 256, 0, stream>>>(x, w_qkv, w_out, Xb, WqT, WoT);

    gemm_bf16_kernel<3*D_MODEL, true><<<dim3(24, 32), 256, 0, stream>>>(
        Xb, WqT, Qb, Kb, Vb, nullptr);
    // causal attention: paired q-tiles, grid = (16, 32) = 512 blocks, 2/CU
    attn_kernel<<<dim3(16, BH), 256, 0, stream>>>(Qb, Kb, Vb, AOb);
    gemm_bf16_kernel<D_MODEL, false><<<dim3(8, 32), 256, 0, stream>>>(
        AOb, WoT, nullptr, nullptr, nullptr, out);
}

// Round 22
// 119.729 us; speedup vs baseline: 1.2700x; 1.0280x over previous
//
#include <hip/hip_runtime.h>
#include <hip/hip_bf16.h>
#include <cstddef>

#define D_MODEL 1024
#define NHEAD   16
#define HD      64
#define BATCH   2
#define SEQ     2048
#define BH      (BATCH*NHEAD)   // 32

typedef short bf16x8 __attribute__((ext_vector_type(8)));
typedef float f32x4  __attribute__((ext_vector_type(4)));

static __device__ __forceinline__ unsigned short f2bf(float f) {
    __hip_bfloat16 h = __float2bfloat16(f);   // RNE
    return __builtin_bit_cast(unsigned short, h);
}
static __device__ __forceinline__ unsigned int pk2(float a, float b) {
    return (unsigned int)f2bf(a) | ((unsigned int)f2bf(b) << 16);
}

// global -> LDS async DMA, 16B per lane: LDS dest = uniform base + lane*16.
#define GLD16(gp, lp) __builtin_amdgcn_global_load_lds( \
    (const __attribute__((address_space(1))) unsigned int*)(gp), \
    (__attribute__((address_space(3))) unsigned int*)(lp), 16, 0, 0)

// ---------------------------------------------------------------------------
// K0: ONE launch for all input prep. Unchanged (R17-R21).
// ---------------------------------------------------------------------------
__global__ __launch_bounds__(256) void cvt_all_kernel(
    const float* __restrict__ x, const float* __restrict__ Wq,
    const float* __restrict__ Wo, unsigned short* __restrict__ Xb,
    unsigned short* __restrict__ WqT, unsigned short* __restrict__ WoT)
{
    __shared__ float T[32][33];
    const int bid = blockIdx.x;
    const int tid = threadIdx.x;
    if (bid < 4096) {
        const int bx = bid & 127;         // n-tile
        const int k0 = (bid >> 7) * 32;   // k-tile
        const float* W; unsigned short* WT; int N, n0;
        if (bx < 96) { W = Wq; WT = WqT; N = 3072; n0 = bx*32; }
        else         { W = Wo; WT = WoT; N = 1024; n0 = (bx-96)*32; }
        const int r  = tid >> 3;          // 0..31
        const int cg = tid & 7;           // 0..7
        float4 v = *(const float4*)&W[(size_t)(k0 + r)*N + n0 + cg*4];
        T[r][cg*4+0] = v.x; T[r][cg*4+1] = v.y;
        T[r][cg*4+2] = v.z; T[r][cg*4+3] = v.w;
        __syncthreads();
        uint2 w;
        w.x = pk2(T[cg*4+0][r], T[cg*4+1][r]);
        w.y = pk2(T[cg*4+2][r], T[cg*4+3][r]);
        *(uint2*)&WT[(size_t)(n0 + r)*1024 + k0 + cg*4] = w;
    } else {
        const int n8 = (BATCH*SEQ*D_MODEL)/8;
        const int stride = 1024 * 256;
        for (int i = (bid - 4096)*256 + tid; i < n8; i += stride) {
            const float4 a = ((const float4*)x)[i*2];
            const float4 b = ((const float4*)x)[i*2+1];
            uint4 w;
            w.x = pk2(a.x, a.y); w.y = pk2(a.z, a.w);
            w.z = pk2(b.x, b.y); w.w = pk2(b.z, b.w);
            ((uint4*)Xb)[i] = w;
        }
    }
}

// ---------------------------------------------------------------------------
// K1/K3 v4: bf16 MFMA GEMM with global_load_lds staging + T1 XCD swizzle.
// Blocks sharing an A-panel (same y) were consecutive in x -> spread over
// all 8 XCD L2s, each refetching A. Remap: XCD x owns 4 m-panels.
//   id = bx + NXT*by; y_eff = 4*(id&7) + (id>>3)/NXT; x_eff = (id>>3)%NXT.
// Bijective (per XCD: 4 panels x NXT n-tiles). A-set/XCD: 8MB -> 1MB.
// ---------------------------------------------------------------------------
template<int NN, bool QKV>
__global__ __launch_bounds__(256, 3) void gemm_bf16_kernel(
    const unsigned short* __restrict__ A, const unsigned short* __restrict__ BT,
    unsigned short* __restrict__ Qo, unsigned short* __restrict__ Ko,
    unsigned short* __restrict__ Vo, float* __restrict__ Cf)
{
    __shared__ __align__(16) unsigned short As[128*32];
    __shared__ __align__(16) unsigned short Bs[128*32];

    constexpr int NXT = NN / 128;         // n-tiles: 24 (qkv) or 8 (out)
    const int id  = blockIdx.x + NXT * blockIdx.y;
    const int jj  = id >> 3;
    const int by  = 4 * (id & 7) + jj / NXT;
    const int bxe = jj % NXT;

    const int tid  = threadIdx.x;
    const int wv   = tid >> 6;
    const int l    = tid & 63;
    const int ln   = l & 15;
    const int lg   = l >> 4;
    const int wrow = (wv >> 1) * 64;
    const int wcol = (wv & 1) * 64;
    const int mtile = by * 128;
    const int ntile = bxe * 128;

    const int c0 = wv*128 + l;
    const int c1 = c0 + 64;
    const int r0 = c0 >> 2, ks0 = ((c0 & 3) ^ ((r0 + (r0 >> 2)) & 3)) * 8;
    const int r1 = c1 >> 2, ks1 = ((c1 & 3) ^ ((r1 + (r1 >> 2)) & 3)) * 8;
    const size_t gA0 = (size_t)(mtile + r0)*1024 + ks0;
    const size_t gA1 = (size_t)(mtile + r1)*1024 + ks1;
    const size_t gB0 = (size_t)(ntile + r0)*1024 + ks0;
    const size_t gB1 = (size_t)(ntile + r1)*1024 + ks1;
    unsigned short* lA0 = &As[(wv*128     ) * 8];
    unsigned short* lA1 = &As[(wv*128 + 64) * 8];
    unsigned short* lB0 = &Bs[(wv*128     ) * 8];
    unsigned short* lB1 = &Bs[(wv*128 + 64) * 8];

    const int sw = ((lg ^ ((ln + (ln >> 2)) & 3))) * 8;

    f32x4 acc[4][4] = {};

    for (int kb = 0; kb < 32; ++kb) {
        const int koff = kb * 32;
        GLD16(A  + gA0 + koff, lA0);
        GLD16(A  + gA1 + koff, lA1);
        GLD16(BT + gB0 + koff, lB0);
        GLD16(BT + gB1 + koff, lB1);
        __syncthreads();
        bf16x8 af[4], bf[4];
        #pragma unroll
        for (int i = 0; i < 4; ++i)
            af[i] = *(const bf16x8*)&As[(wrow + i*16 + ln)*32 + sw];
        #pragma unroll
        for (int j = 0; j < 4; ++j)
            bf[j] = *(const bf16x8*)&Bs[(wcol + j*16 + ln)*32 + sw];
        #pragma unroll
        for (int i = 0; i < 4; ++i)
            #pragma unroll
            for (int j = 0; j < 4; ++j)
                acc[i][j] = __builtin_amdgcn_mfma_f32_16x16x32_bf16(af[i], bf[j], acc[i][j], 0, 0, 0);
        __syncthreads();
    }

    #pragma unroll
    for (int i = 0; i < 4; ++i) {
        #pragma unroll
        for (int r = 0; r < 4; ++r) {
            const int mm = mtile + wrow + i*16 + lg*4 + r;
            if constexpr (QKV) {
                const int bb = mm >> 11;
                const int ss = mm & 2047;
                #pragma unroll
                for (int j = 0; j < 4; ++j) {
                    const int cb  = ntile + wcol + j*16 + ln;
                    const int wch = cb >> 10;
                    const int rem = cb & 1023;
                    const int h   = rem >> 6;
                    const int dd  = rem & 63;
                    unsigned short* dstBase = (wch == 0) ? Qo : (wch == 1) ? Ko : Vo;
                    dstBase[((size_t)(bb*NHEAD + h)*SEQ + ss)*HD + dd] = f2bf(acc[i][j][r]);
                }
            } else {
                #pragma unroll
                for (int j = 0; j < 4; ++j) {
                    const int cb = ntile + wcol + j*16 + ln;
                    Cf[(size_t)mm*NN + cb] = acc[i][j][r];
                }
            }
        }
    }
}

// ---------------------------------------------------------------------------
// K2 v15 = v13 body (61.4 us, R19/R21) + T1 XCD swizzle of (bx,bh) only.
// The 16 blocks sharing one head's K/V were consecutive in x -> all 8 XCD
// L2s fetched copies (FETCH 96MB vs 24MB compulsory). Remap: XCD x owns
// heads 4x..4x+3 (K/V set 2MB < 4MB L2):
//   id = blockIdx.x + 16*blockIdx.y; bh = 4*(id&7) + (id>>3)/16;
//   bx = (id>>3) & 15.  Bijective. Kernel body untouched.
// ---------------------------------------------------------------------------
__global__ __launch_bounds__(256, 2) void attn_kernel(
    const unsigned short* __restrict__ Qb, const unsigned short* __restrict__ Kb,
    const unsigned short* __restrict__ Vb, unsigned short* __restrict__ AO)
{
    __shared__ __align__(16) unsigned short Ks[2][64][72];  // keys x dims(+pad)
    __shared__ __align__(16) unsigned short Vt[2][64][72];  // dims x keys(+pad)
    __shared__ __align__(16) unsigned short Pl[4][16][76];  // per-wave P^T

    const int tid = threadIdx.x;
    const int wv  = tid >> 6;
    const int l   = tid & 63;
    const int ln  = l & 15;
    const int lg  = l >> 4;
    const int id  = blockIdx.x + 16*blockIdx.y;   // 0..511
    const int jj  = id >> 3;
    const int bh  = 4*(id & 7) + (jj >> 4);       // XCD-clustered head
    const int bx  = jj & 15;
    const int qtA = 31 - bx;
    const int qtB = bx;
    const int nTA = qtA + 1;
    const int nT  = nTA + qtB + 1;       // 33 always

    const unsigned short* Qbh = Qb + (size_t)bh*SEQ*HD;
    const unsigned short* Kbh = Kb + (size_t)bh*SEQ*HD;
    const unsigned short* Vbh = Vb + (size_t)bh*SEQ*HD;

    const int s_kl = tid >> 3;
    const int s_d0 = (tid & 7) << 3;
    const int s_dg = tid >> 4;
    const int s_kp = (tid & 15) << 1;

    auto ktOf = [&](int t) { return (t < nTA ? t : t - nTA) * 64; };

    // T14 split: global->regs (issue early) vs regs->LDS (write late)
    uint4 rk0, rk1;
    uint2 rva0, rvb0, rva1, rvb1;
    auto load_tile = [&](int kt) {
        rk0  = *(const uint4*)&Kbh[(size_t)(kt + s_kl     )*HD + s_d0];
        rk1  = *(const uint4*)&Kbh[(size_t)(kt + s_kl + 32)*HD + s_d0];
        rva0 = *(const uint2*)&Vbh[(size_t)(kt + s_kp     )*HD + s_dg*4];
        rvb0 = *(const uint2*)&Vbh[(size_t)(kt + s_kp + 1 )*HD + s_dg*4];
        rva1 = *(const uint2*)&Vbh[(size_t)(kt + s_kp + 32)*HD + s_dg*4];
        rvb1 = *(const uint2*)&Vbh[(size_t)(kt + s_kp + 33)*HD + s_dg*4];
    };
    auto write_tile = [&](int nb) {
        *(uint4*)&Ks[nb][s_kl     ][s_d0] = rk0;
        *(uint4*)&Ks[nb][s_kl + 32][s_d0] = rk1;
        *(unsigned int*)&Vt[nb][s_dg*4+0][s_kp]    = (rva0.x & 0xffffu) | (rvb0.x << 16);
        *(unsigned int*)&Vt[nb][s_dg*4+1][s_kp]    = (rva0.x >> 16)     | (rvb0.x & 0xffff0000u);
        *(unsigned int*)&Vt[nb][s_dg*4+2][s_kp]    = (rva0.y & 0xffffu) | (rvb0.y << 16);
        *(unsigned int*)&Vt[nb][s_dg*4+3][s_kp]    = (rva0.y >> 16)     | (rvb0.y & 0xffff0000u);
        *(unsigned int*)&Vt[nb][s_dg*4+0][s_kp+32] = (rva1.x & 0xffffu) | (rvb1.x << 16);
        *(unsigned int*)&Vt[nb][s_dg*4+1][s_kp+32] = (rva1.x >> 16)     | (rvb1.x & 0xffff0000u);
        *(unsigned int*)&Vt[nb][s_dg*4+2][s_kp+32] = (rva1.y & 0xffffu) | (rvb1.y << 16);
        *(unsigned int*)&Vt[nb][s_dg*4+3][s_kp+32] = (rva1.y >> 16)     | (rvb1.y & 0xffff0000u);
    };

    int qrow0 = qtA*64 + wv*16;
    bf16x8 q0 = *(const bf16x8*)&Qbh[(size_t)(qrow0 + ln)*HD + lg*8];
    bf16x8 q1 = *(const bf16x8*)&Qbh[(size_t)(qrow0 + ln)*HD + 32 + lg*8];

    f32x4 o[4] = {};
    float m = -1e30f, lsum = 0.f;

    auto epilogue = [&](int qr0) {
        const int bb = bh >> 4;
        const int h  = bh & 15;
        const float inv = 1.f / lsum;
        const size_t base = ((size_t)bb*SEQ + qr0 + ln)*D_MODEL + h*HD + lg*4;
        #pragma unroll
        for (int f = 0; f < 4; ++f) {
            uint2 w;
            w.x = pk2(o[f][0]*inv, o[f][1]*inv);
            w.y = pk2(o[f][2]*inv, o[f][3]*inv);
            *(uint2*)&AO[base + f*16] = w;
        }
    };

    // prologue: tile 0 staged synchronously; tile 1 loads issued early
    load_tile(0);
    write_tile(0);
    if (nT > 1) load_tile(ktOf(1));

    for (int t = 0; t < nT; ++t) {
        __syncthreads();                     // publishes buf[t&1]
        const int buf = t & 1;
        const int kt = ktOf(t);

        // ---- QK^T swapped: S^T(64keys x 16q)
        f32x4 s[4];
        #pragma unroll
        for (int g = 0; g < 4; ++g) {
            bf16x8 ka = *(const bf16x8*)&Ks[buf][g*16 + ln][lg*8];
            bf16x8 kb = *(const bf16x8*)&Ks[buf][g*16 + ln][32 + lg*8];
            f32x4 sg = {};
            sg = __builtin_amdgcn_mfma_f32_16x16x32_bf16(ka, q0, sg, 0, 0, 0);
            sg = __builtin_amdgcn_mfma_f32_16x16x32_bf16(kb, q1, sg, 0, 0, 0);
            s[g] = sg;
        }

        const int qg = qrow0 + ln;
        const int kbase = kt + lg*4;
        float mx = -1e30f;
        #pragma unroll
        for (int g = 0; g < 4; ++g) {
            #pragma unroll
            for (int r = 0; r < 4; ++r) {
                float v = s[g][r] * 0.125f;
                v = (kbase + g*16 + r > qg) ? -1e30f : v;
                s[g][r] = v;
                mx = fmaxf(mx, v);
            }
        }
        mx = fmaxf(mx, __shfl_xor(mx, 16));
        mx = fmaxf(mx, __shfl_xor(mx, 32));

        if (__any(mx > m)) {
            const float mnew = fmaxf(m, mx);
            const float alpha = __expf(m - mnew);
            m = mnew;
            lsum *= alpha;
            #pragma unroll
            for (int f = 0; f < 4; ++f)
                #pragma unroll
                for (int r = 0; r < 4; ++r) o[f][r] *= alpha;
        }
        float ps = 0.f;
        #pragma unroll
        for (int g = 0; g < 4; ++g) {
            #pragma unroll
            for (int r = 0; r < 4; ++r) {
                const float e = __expf(s[g][r] - m);
                s[g][r] = e;
                ps += e;
            }
        }
        ps += __shfl_xor(ps, 16);
        ps += __shfl_xor(ps, 32);
        lsum += ps;

        #pragma unroll
        for (int g = 0; g < 4; ++g) {
            unsigned long long w =
                (unsigned long long)pk2(s[g][0], s[g][1]) |
                ((unsigned long long)pk2(s[g][2], s[g][3]) << 32);
            *(unsigned long long*)&Pl[wv][ln][g*16 + lg*4] = w;
        }
        bf16x8 pb0 = *(const bf16x8*)&Pl[wv][ln][lg*8];
        bf16x8 pb1 = *(const bf16x8*)&Pl[wv][ln][32 + lg*8];

        #pragma unroll
        for (int f = 0; f < 4; ++f) {
            bf16x8 v0 = *(const bf16x8*)&Vt[buf][f*16 + ln][lg*8];
            bf16x8 v1 = *(const bf16x8*)&Vt[buf][f*16 + ln][32 + lg*8];
            o[f] = __builtin_amdgcn_mfma_f32_16x16x32_bf16(v0, pb0, o[f], 0, 0, 0);
            o[f] = __builtin_amdgcn_mfma_f32_16x16x32_bf16(v1, pb1, o[f], 0, 0, 0);
        }

        // ---- late stage write for t+1, then issue loads for t+2
        if (t + 1 < nT) {
            write_tile(buf ^ 1);
            if (t + 2 < nT) load_tile(ktOf(t + 2));
        }

        // ---- phase boundary: flush q-tile A, reset for q-tile B
        if (t == nTA - 1) {
            epilogue(qrow0);
            qrow0 = qtB*64 + wv*16;
            q0 = *(const bf16x8*)&Qbh[(size_t)(qrow0 + ln)*HD + lg*8];
            q1 = *(const bf16x8*)&Qbh[(size_t)(qrow0 + ln)*HD + 32 + lg*8];
            m = -1e30f; lsum = 0.f;
            #pragma unroll
            for (int f = 0; f < 4; ++f)
                #pragma unroll
                for (int r = 0; r < 4; ++r) o[f][r] = 0.f;
        }
    }
    epilogue(qrow0);   // q-tile B
}

// ---------------------------------------------------------------------------
extern "C" void kernel_launch(void* const* d_in, const int* in_sizes, int n_in,
                              void* d_out, int out_size, void* d_ws, size_t ws_size,
                              hipStream_t stream)
{
    const float* x     = (const float*)d_in[0];   // (2,2048,1024)
    const float* w_qkv = (const float*)d_in[1];   // (1024,3072)
    const float* w_out = (const float*)d_in[2];   // (1024,1024)
    float* out = (float*)d_out;                   // (2,2048,1024)

    const size_t nX  = (size_t)BATCH*SEQ*D_MODEL;      // 4 Mi
    const size_t nWq = (size_t)D_MODEL*3*D_MODEL;      // 3 Mi
    const size_t nWo = (size_t)D_MODEL*D_MODEL;        // 1 Mi
    const size_t per = (size_t)BH * SEQ * HD;          // 4 Mi

    unsigned short* Xb   = (unsigned short*)d_ws;      // bf16 x (M x K)
    unsigned short* WqT  = Xb   + nX;                  // bf16 w_qkv^T
    unsigned short* WoT  = WqT  + nWq;                 // bf16 w_out^T
    unsigned short* Qb   = WoT  + nWo;
    unsigned short* Kb   = Qb + per;
    unsigned short* Vb   = Kb + per;
    unsigned short* AOb  = Vb + per;                   // bf16 (B,S,D)

    // all input prep in one launch: 4096 transpose blocks + 1024 cvt blocks
    cvt_all_kernel<<<5120, 256, 0, stream>>>(x, w_qkv, w_out, Xb, WqT, WoT);

    gemm_bf16_kernel<3*D_MODEL, true><<<dim3(24, 32), 256, 0, stream>>>(
        Xb, WqT, Qb, Kb, Vb, nullptr);
    // causal attention: paired q-tiles, grid = (16, 32) = 512 blocks, 2/CU
    attn_kernel<<<dim3(16, BH), 256, 0, stream>>>(Qb, Kb, Vb, AOb);
    gemm_bf16_kernel<D_MODEL, false><<<dim3(8, 32), 256, 0, stream>>>(
        AOb, WoT, nullptr, nullptr, nullptr, out);
}

// Round 25
// 119.620 us; speedup vs baseline: 1.2712x; 1.0009x over previous
//
#include <hip/hip_runtime.h>
#include <hip/hip_bf16.h>
#include <cstddef>

#define D_MODEL 1024
#define NHEAD   16
#define HD      64
#define BATCH   2
#define SEQ     2048
#define BH      (BATCH*NHEAD)   // 32

typedef short bf16x8 __attribute__((ext_vector_type(8)));
typedef float f32x4  __attribute__((ext_vector_type(4)));

static __device__ __forceinline__ unsigned short f2bf(float f) {
    __hip_bfloat16 h = __float2bfloat16(f);   // RNE
    return __builtin_bit_cast(unsigned short, h);
}
static __device__ __forceinline__ unsigned int pk2(float a, float b) {
    return (unsigned int)f2bf(a) | ((unsigned int)f2bf(b) << 16);
}

// global -> LDS async DMA, 16B per lane: LDS dest = uniform base + lane*16.
#define GLD16(gp, lp) __builtin_amdgcn_global_load_lds( \
    (const __attribute__((address_space(1))) unsigned int*)(gp), \
    (__attribute__((address_space(3))) unsigned int*)(lp), 16, 0, 0)

// ---------------------------------------------------------------------------
// K0: ONE launch for all input prep. Unchanged (R17-R22).
// ---------------------------------------------------------------------------
__global__ __launch_bounds__(256) void cvt_all_kernel(
    const float* __restrict__ x, const float* __restrict__ Wq,
    const float* __restrict__ Wo, unsigned short* __restrict__ Xb,
    unsigned short* __restrict__ WqT, unsigned short* __restrict__ WoT)
{
    __shared__ float T[32][33];
    const int bid = blockIdx.x;
    const int tid = threadIdx.x;
    if (bid < 4096) {
        const int bx = bid & 127;         // n-tile
        const int k0 = (bid >> 7) * 32;   // k-tile
        const float* W; unsigned short* WT; int N, n0;
        if (bx < 96) { W = Wq; WT = WqT; N = 3072; n0 = bx*32; }
        else         { W = Wo; WT = WoT; N = 1024; n0 = (bx-96)*32; }
        const int r  = tid >> 3;          // 0..31
        const int cg = tid & 7;           // 0..7
        float4 v = *(const float4*)&W[(size_t)(k0 + r)*N + n0 + cg*4];
        T[r][cg*4+0] = v.x; T[r][cg*4+1] = v.y;
        T[r][cg*4+2] = v.z; T[r][cg*4+3] = v.w;
        __syncthreads();
        uint2 w;
        w.x = pk2(T[cg*4+0][r], T[cg*4+1][r]);
        w.y = pk2(T[cg*4+2][r], T[cg*4+3][r]);
        *(uint2*)&WT[(size_t)(n0 + r)*1024 + k0 + cg*4] = w;
    } else {
        const int n8 = (BATCH*SEQ*D_MODEL)/8;
        const int stride = 1024 * 256;
        for (int i = (bid - 4096)*256 + tid; i < n8; i += stride) {
            const float4 a = ((const float4*)x)[i*2];
            const float4 b = ((const float4*)x)[i*2+1];
            uint4 w;
            w.x = pk2(a.x, a.y); w.y = pk2(a.z, a.w);
            w.z = pk2(b.x, b.y); w.w = pk2(b.z, b.w);
            ((uint4*)Xb)[i] = w;
        }
    }
}

// ---------------------------------------------------------------------------
// K1/K3 v4: bf16 MFMA GEMM, global_load_lds staging + T1 XCD swizzle.
// Unchanged (R22).
// ---------------------------------------------------------------------------
template<int NN, bool QKV>
__global__ __launch_bounds__(256, 3) void gemm_bf16_kernel(
    const unsigned short* __restrict__ A, const unsigned short* __restrict__ BT,
    unsigned short* __restrict__ Qo, unsigned short* __restrict__ Ko,
    unsigned short* __restrict__ Vo, float* __restrict__ Cf)
{
    __shared__ __align__(16) unsigned short As[128*32];
    __shared__ __align__(16) unsigned short Bs[128*32];

    constexpr int NXT = NN / 128;         // n-tiles: 24 (qkv) or 8 (out)
    const int id  = blockIdx.x + NXT * blockIdx.y;
    const int jj  = id >> 3;
    const int by  = 4 * (id & 7) + jj / NXT;
    const int bxe = jj % NXT;

    const int tid  = threadIdx.x;
    const int wv   = tid >> 6;
    const int l    = tid & 63;
    const int ln   = l & 15;
    const int lg   = l >> 4;
    const int wrow = (wv >> 1) * 64;
    const int wcol = (wv & 1) * 64;
    const int mtile = by * 128;
    const int ntile = bxe * 128;

    const int c0 = wv*128 + l;
    const int c1 = c0 + 64;
    const int r0 = c0 >> 2, ks0 = ((c0 & 3) ^ ((r0 + (r0 >> 2)) & 3)) * 8;
    const int r1 = c1 >> 2, ks1 = ((c1 & 3) ^ ((r1 + (r1 >> 2)) & 3)) * 8;
    const size_t gA0 = (size_t)(mtile + r0)*1024 + ks0;
    const size_t gA1 = (size_t)(mtile + r1)*1024 + ks1;
    const size_t gB0 = (size_t)(ntile + r0)*1024 + ks0;
    const size_t gB1 = (size_t)(ntile + r1)*1024 + ks1;
    unsigned short* lA0 = &As[(wv*128     ) * 8];
    unsigned short* lA1 = &As[(wv*128 + 64) * 8];
    unsigned short* lB0 = &Bs[(wv*128     ) * 8];
    unsigned short* lB1 = &Bs[(wv*128 + 64) * 8];

    const int sw = ((lg ^ ((ln + (ln >> 2)) & 3))) * 8;

    f32x4 acc[4][4] = {};

    for (int kb = 0; kb < 32; ++kb) {
        const int koff = kb * 32;
        GLD16(A  + gA0 + koff, lA0);
        GLD16(A  + gA1 + koff, lA1);
        GLD16(BT + gB0 + koff, lB0);
        GLD16(BT + gB1 + koff, lB1);
        __syncthreads();
        bf16x8 af[4], bf[4];
        #pragma unroll
        for (int i = 0; i < 4; ++i)
            af[i] = *(const bf16x8*)&As[(wrow + i*16 + ln)*32 + sw];
        #pragma unroll
        for (int j = 0; j < 4; ++j)
            bf[j] = *(const bf16x8*)&Bs[(wcol + j*16 + ln)*32 + sw];
        #pragma unroll
        for (int i = 0; i < 4; ++i)
            #pragma unroll
            for (int j = 0; j < 4; ++j)
                acc[i][j] = __builtin_amdgcn_mfma_f32_16x16x32_bf16(af[i], bf[j], acc[i][j], 0, 0, 0);
        __syncthreads();
    }

    #pragma unroll
    for (int i = 0; i < 4; ++i) {
        #pragma unroll
        for (int r = 0; r < 4; ++r) {
            const int mm = mtile + wrow + i*16 + lg*4 + r;
            if constexpr (QKV) {
                const int bb = mm >> 11;
                const int ss = mm & 2047;
                #pragma unroll
                for (int j = 0; j < 4; ++j) {
                    const int cb  = ntile + wcol + j*16 + ln;
                    const int wch = cb >> 10;
                    const int rem = cb & 1023;
                    const int h   = rem >> 6;
                    const int dd  = rem & 63;
                    unsigned short* dstBase = (wch == 0) ? Qo : (wch == 1) ? Ko : Vo;
                    dstBase[((size_t)(bb*NHEAD + h)*SEQ + ss)*HD + dd] = f2bf(acc[i][j][r]);
                }
            } else {
                #pragma unroll
                for (int j = 0; j < 4; ++j) {
                    const int cb = ntile + wcol + j*16 + ln;
                    Cf[(size_t)mm*NN + cb] = acc[i][j][r];
                }
            }
        }
    }
}

// ---------------------------------------------------------------------------
// K2 v15 (R22, 60.8 us, passing). Structure: swapped QK^T (per-lane scalar
// m/lsum, 2-level shfl_xor), KVBLK=64, paired q-tiles (33 tiles/block),
// T14 async-STAGE, defer-max, T1 XCD head-clustering (FETCH 96->12.4 MB).
// ---------------------------------------------------------------------------
__global__ __launch_bounds__(256, 2) void attn_kernel(
    const unsigned short* __restrict__ Qb, const unsigned short* __restrict__ Kb,
    const unsigned short* __restrict__ Vb, unsigned short* __restrict__ AO)
{
    __shared__ __align__(16) unsigned short Ks[2][64][72];  // keys x dims(+pad)
    __shared__ __align__(16) unsigned short Vt[2][64][72];  // dims x keys(+pad)
    __shared__ __align__(16) unsigned short Pl[4][16][76];  // per-wave P^T

    const int tid = threadIdx.x;
    const int wv  = tid >> 6;
    const int l   = tid & 63;
    const int ln  = l & 15;
    const int lg  = l >> 4;
    const int id  = blockIdx.x + 16*blockIdx.y;   // 0..511
    const int jj  = id >> 3;
    const int bh  = 4*(id & 7) + (jj >> 4);       // XCD-clustered head
    const int bx  = jj & 15;
    const int qtA = 31 - bx;
    const int qtB = bx;
    const int nTA = qtA + 1;
    const int nT  = nTA + qtB + 1;       // 33 always

    const unsigned short* Qbh = Qb + (size_t)bh*SEQ*HD;
    const unsigned short* Kbh = Kb + (size_t)bh*SEQ*HD;
    const unsigned short* Vbh = Vb + (size_t)bh*SEQ*HD;

    const int s_kl = tid >> 3;
    const int s_d0 = (tid & 7) << 3;
    const int s_dg = tid >> 4;
    const int s_kp = (tid & 15) << 1;

    auto ktOf = [&](int t) { return (t < nTA ? t : t - nTA) * 64; };

    // T14 split: global->regs (issue early) vs regs->LDS (write late)
    uint4 rk0, rk1;
    uint2 rva0, rvb0, rva1, rvb1;
    auto load_tile = [&](int kt) {
        rk0  = *(const uint4*)&Kbh[(size_t)(kt + s_kl     )*HD + s_d0];
        rk1  = *(const uint4*)&Kbh[(size_t)(kt + s_kl + 32)*HD + s_d0];
        rva0 = *(const uint2*)&Vbh[(size_t)(kt + s_kp     )*HD + s_dg*4];
        rvb0 = *(const uint2*)&Vbh[(size_t)(kt + s_kp + 1 )*HD + s_dg*4];
        rva1 = *(const uint2*)&Vbh[(size_t)(kt + s_kp + 32)*HD + s_dg*4];
        rvb1 = *(const uint2*)&Vbh[(size_t)(kt + s_kp + 33)*HD + s_dg*4];
    };
    auto write_tile = [&](int nb) {
        *(uint4*)&Ks[nb][s_kl     ][s_d0] = rk0;
        *(uint4*)&Ks[nb][s_kl + 32][s_d0] = rk1;
        *(unsigned int*)&Vt[nb][s_dg*4+0][s_kp]    = (rva0.x & 0xffffu) | (rvb0.x << 16);
        *(unsigned int*)&Vt[nb][s_dg*4+1][s_kp]    = (rva0.x >> 16)     | (rvb0.x & 0xffff0000u);
        *(unsigned int*)&Vt[nb][s_dg*4+2][s_kp]    = (rva0.y & 0xffffu) | (rvb0.y << 16);
        *(unsigned int*)&Vt[nb][s_dg*4+3][s_kp]    = (rva0.y >> 16)     | (rvb0.y & 0xffff0000u);
        *(unsigned int*)&Vt[nb][s_dg*4+0][s_kp+32] = (rva1.x & 0xffffu) | (rvb1.x << 16);
        *(unsigned int*)&Vt[nb][s_dg*4+1][s_kp+32] = (rva1.x >> 16)     | (rvb1.x & 0xffff0000u);
        *(unsigned int*)&Vt[nb][s_dg*4+2][s_kp+32] = (rva1.y & 0xffffu) | (rvb1.y << 16);
        *(unsigned int*)&Vt[nb][s_dg*4+3][s_kp+32] = (rva1.y >> 16)     | (rvb1.y & 0xffff0000u);
    };

    int qrow0 = qtA*64 + wv*16;
    bf16x8 q0 = *(const bf16x8*)&Qbh[(size_t)(qrow0 + ln)*HD + lg*8];
    bf16x8 q1 = *(const bf16x8*)&Qbh[(size_t)(qrow0 + ln)*HD + 32 + lg*8];

    f32x4 o[4] = {};
    float m = -1e30f, lsum = 0.f;

    auto epilogue = [&](int qr0) {
        const int bb = bh >> 4;
        const int h  = bh & 15;
        const float inv = 1.f / lsum;
        const size_t base = ((size_t)bb*SEQ + qr0 + ln)*D_MODEL + h*HD + lg*4;
        #pragma unroll
        for (int f = 0; f < 4; ++f) {
            uint2 w;
            w.x = pk2(o[f][0]*inv, o[f][1]*inv);
            w.y = pk2(o[f][2]*inv, o[f][3]*inv);
            *(uint2*)&AO[base + f*16] = w;
        }
    };

    // prologue: tile 0 staged synchronously; tile 1 loads issued early
    load_tile(0);
    write_tile(0);
    if (nT > 1) load_tile(ktOf(1));

    for (int t = 0; t < nT; ++t) {
        __syncthreads();                     // publishes buf[t&1]
        const int buf = t & 1;
        const int kt = ktOf(t);

        // ---- QK^T swapped: S^T(64keys x 16q)
        f32x4 s[4];
        #pragma unroll
        for (int g = 0; g < 4; ++g) {
            bf16x8 ka = *(const bf16x8*)&Ks[buf][g*16 + ln][lg*8];
            bf16x8 kb = *(const bf16x8*)&Ks[buf][g*16 + ln][32 + lg*8];
            f32x4 sg = {};
            sg = __builtin_amdgcn_mfma_f32_16x16x32_bf16(ka, q0, sg, 0, 0, 0);
            sg = __builtin_amdgcn_mfma_f32_16x16x32_bf16(kb, q1, sg, 0, 0, 0);
            s[g] = sg;
        }

        const int qg = qrow0 + ln;
        const int kbase = kt + lg*4;
        float mx = -1e30f;
        #pragma unroll
        for (int g = 0; g < 4; ++g) {
            #pragma unroll
            for (int r = 0; r < 4; ++r) {
                float v = s[g][r] * 0.125f;
                v = (kbase + g*16 + r > qg) ? -1e30f : v;
                s[g][r] = v;
                mx = fmaxf(mx, v);
            }
        }
        mx = fmaxf(mx, __shfl_xor(mx, 16));
        mx = fmaxf(mx, __shfl_xor(mx, 32));

        if (__any(mx > m)) {
            const float mnew = fmaxf(m, mx);
            const float alpha = __expf(m - mnew);
            m = mnew;
            lsum *= alpha;
            #pragma unroll
            for (int f = 0; f < 4; ++f)
                #pragma unroll
                for (int r = 0; r < 4; ++r) o[f][r] *= alpha;
        }
        float ps = 0.f;
        #pragma unroll
        for (int g = 0; g < 4; ++g) {
            #pragma unroll
            for (int r = 0; r < 4; ++r) {
                const float e = __expf(s[g][r] - m);
                s[g][r] = e;
                ps += e;
            }
        }
        ps += __shfl_xor(ps, 16);
        ps += __shfl_xor(ps, 32);
        lsum += ps;

        #pragma unroll
        for (int g = 0; g < 4; ++g) {
            unsigned long long w =
                (unsigned long long)pk2(s[g][0], s[g][1]) |
                ((unsigned long long)pk2(s[g][2], s[g][3]) << 32);
            *(unsigned long long*)&Pl[wv][ln][g*16 + lg*4] = w;
        }
        bf16x8 pb0 = *(const bf16x8*)&Pl[wv][ln][lg*8];
        bf16x8 pb1 = *(const bf16x8*)&Pl[wv][ln][32 + lg*8];

        #pragma unroll
        for (int f = 0; f < 4; ++f) {
            bf16x8 v0 = *(const bf16x8*)&Vt[buf][f*16 + ln][lg*8];
            bf16x8 v1 = *(const bf16x8*)&Vt[buf][f*16 + ln][32 + lg*8];
            o[f] = __builtin_amdgcn_mfma_f32_16x16x32_bf16(v0, pb0, o[f], 0, 0, 0);
            o[f] = __builtin_amdgcn_mfma_f32_16x16x32_bf16(v1, pb1, o[f], 0, 0, 0);
        }

        // ---- late stage write for t+1, then issue loads for t+2
        if (t + 1 < nT) {
            write_tile(buf ^ 1);
            if (t + 2 < nT) load_tile(ktOf(t + 2));
        }

        // ---- phase boundary: flush q-tile A, reset for q-tile B
        if (t == nTA - 1) {
            epilogue(qrow0);
            qrow0 = qtB*64 + wv*16;
            q0 = *(const bf16x8*)&Qbh[(size_t)(qrow0 + ln)*HD + lg*8];
            q1 = *(const bf16x8*)&Qbh[(size_t)(qrow0 + ln)*HD + 32 + lg*8];
            m = -1e30f; lsum = 0.f;
            #pragma unroll
            for (int f = 0; f < 4; ++f)
                #pragma unroll
                for (int r = 0; r < 4; ++r) o[f][r] = 0.f;
        }
    }
    epilogue(qrow0);   // q-tile B
}

// ---------------------------------------------------------------------------
extern "C" void kernel_launch(void* const* d_in, const int* in_sizes, int n_in,
                              void* d_out, int out_size, void* d_ws, size_t ws_size,
                              hipStream_t stream)
{
    const float* x     = (const float*)d_in[0];   // (2,2048,1024)
    const float* w_qkv = (const float*)d_in[1];   // (1024,3072)
    const float* w_out = (const float*)d_in[2];   // (1024,1024)
    float* out = (float*)d_out;                   // (2,2048,1024)

    const size_t nX  = (size_t)BATCH*SEQ*D_MODEL;      // 4 Mi
    const size_t nWq = (size_t)D_MODEL*3*D_MODEL;      // 3 Mi
    const size_t nWo = (size_t)D_MODEL*D_MODEL;        // 1 Mi
    const size_t per = (size_t)BH * SEQ * HD;          // 4 Mi

    unsigned short* Xb   = (unsigned short*)d_ws;      // bf16 x (M x K)
    unsigned short* WqT  = Xb   + nX;                  // bf16 w_qkv^T
    unsigned short* WoT  = WqT  + nWq;                 // bf16 w_out^T
    unsigned short* Qb   = WoT  + nWo;
    unsigned short* Kb   = Qb + per;
    unsigned short* Vb   = Kb + per;
    unsigned short* AOb  = Vb + per;                   // bf16 (B,S,D)

    // all input prep in one launch: 4096 transpose blocks + 1024 cvt blocks
    cvt_all_kernel<<<5120, 256, 0, stream>>>(x, w_qkv, w_out, Xb, WqT, WoT);

    gemm_bf16_kernel<3*D_MODEL, true><<<dim3(24, 32), 256, 0, stream>>>(
        Xb, WqT, Qb, Kb, Vb, nullptr);
    // causal attention: paired q-tiles, grid = (16, 32) = 512 blocks, 2/CU
    attn_kernel<<<dim3(16, BH), 256, 0, stream>>>(Qb, Kb, Vb, AOb);
    gemm_bf16_kernel<D_MODEL, false><<<dim3(8, 32), 256, 0, stream>>>(
        AOb, WoT, nullptr, nullptr, nullptr, out);
}